// Round 18
// baseline (183.733 us; speedup 1.0000x reference)
//
#include <hip/hip_runtime.h>
#include <hip/hip_bf16.h>
#include <cstdint>
#include <cstddef>

#define B_ 4
#define S_ 2048
#define E_ 1024
#define H_ 16
#define BS_ (B_*S_)
#define BHS_ (B_*H_*S_)
#define MAXCAND (1u<<18)
#define SLOTS 512

static constexpr float T_SEARCH = 50.0f;  // bf16 search threshold (~8-sigma over cut)
static constexpr float T_CUT    = 48.5f;  // exact fp32 cut; e^-48.5 contribution ~300x under tol

typedef __attribute__((ext_vector_type(8))) short bf16x8;
typedef __attribute__((ext_vector_type(4))) float f32x4;

static __device__ __forceinline__ unsigned short f32_to_bf16(float f){
  unsigned u = __float_as_uint(f);
  return (unsigned short)((u + 0x7fffu + ((u >> 16) & 1u)) >> 16);  // RNE
}
static __device__ __forceinline__ void gload_lds16(const void* g, void* l){
  __builtin_amdgcn_global_load_lds(
      (const __attribute__((address_space(1))) unsigned int*)g,
      (__attribute__((address_space(3))) unsigned int*)l, 16, 0, 0);
}
static __device__ __forceinline__ float dot4(float4 a, float4 b){
  return a.x*b.x + a.y*b.y + a.z*b.z + a.w*b.w;
}

#define VMW(N_) asm volatile("s_waitcnt vmcnt(" #N_ ")" ::: "memory")
#define BAR()  do{ __builtin_amdgcn_s_barrier(); __builtin_amdgcn_sched_barrier(0); }while(0)

// --- fused: f32->bf16 casts (x, Wq, Wk) + mask compaction + d_out zeroing ---
__global__ void cast_compact_k(const float* __restrict__ x,
                               const float* __restrict__ wq, const float* __restrict__ wk,
                               const int* __restrict__ mask,
                               unsigned short* __restrict__ xb, unsigned short* __restrict__ wqkb,
                               int* __restrict__ tmap, int* __restrict__ vcount,
                               float* __restrict__ outz){
  int blk = blockIdx.x;
  if (blk >= 5124){                     // zero d_out: 2048 blocks x 16KB
    float4* f4 = reinterpret_cast<float4*>(outz + (size_t)(blk - 5124)*4096);
    float4 z = {0.f,0.f,0.f,0.f};
    f4[threadIdx.x]       = z;
    f4[threadIdx.x + 256] = z;
    f4[threadIdx.x + 512] = z;
    f4[threadIdx.x + 768] = z;
    return;
  }
  if (blk >= 5120){                     // mask compaction, b = blk-5120
    int b = blk - 5120, tid = threadIdx.x;
    __shared__ int ps[256];
    int loc[8]; int cnt = 0;
    #pragma unroll
    for (int j = 0; j < 8; ++j){ int m = mask[b*S_ + tid*8 + j]; loc[j] = m; cnt += m; }
    ps[tid] = cnt; __syncthreads();
    for (int off = 1; off < 256; off <<= 1){
      int v = (tid >= off) ? ps[tid-off] : 0;
      __syncthreads(); ps[tid] += v; __syncthreads();
    }
    int base = ps[tid] - cnt;
    #pragma unroll
    for (int j = 0; j < 8; ++j)
      if (loc[j]){ tmap[b*S_ + base] = tid*8 + j; ++base; }
    if (tid == 255) vcount[b] = ps[255];
    return;
  }
  const float* src; unsigned short* dst; int base;
  if (blk < 4096){ src = x;  dst = xb;                  base = blk; }
  else if (blk < 4608){ src = wq; dst = wqkb;           base = blk - 4096; }
  else { src = wk; dst = wqkb + (size_t)E_*E_;          base = blk - 4608; }
  size_t i = (size_t)base*256 + threadIdx.x;            // 8 elems per item
  const float4* s4 = reinterpret_cast<const float4*>(src) + 2*i;
  float4 a = s4[0], b = s4[1];
  float v[8] = {a.x,a.y,a.z,a.w,b.x,b.y,b.z,b.w};
  union { unsigned short us[8]; uint4 u4; } o;
  #pragma unroll
  for (int j = 0; j < 8; ++j) o.us[j] = f32_to_bf16(v[j]);
  reinterpret_cast<uint4*>(dst)[i] = o.u4;
}

// ------- fused Q|K projection, ring-3 pipelined staging (48KB, 3 blocks/CU) -------
// Same 2-deep counted-vmcnt pipeline as the proven dbuf version; ring-3 WAR-safe:
// stage(t+2) overwrites slot (t-1)%3, fenced by two barriers since its last read.
#define PROJ_STAGE(buf_, k0_) do{                                              \
  _Pragma("unroll") for (int i_ = 0; i_ < 4; ++i_){                            \
    int r_  = wave*32 + i_*8 + srow;                                           \
    int cs_ = sc ^ (r_ & 7);                                                   \
    gload_lds16(xb + ((size_t)(bb << 11) + arow[i_])*1024 + (k0_) + cs_*8,     \
                &At[buf_][(wave*32 + i_*8)*64]);                               \
    gload_lds16(Bw + (size_t)(n0 + r_)*1024 + (k0_) + cs_*8,                   \
                &Bt[buf_][(wave*32 + i_*8)*64]);                               \
  }                                                                            \
}while(0)

#define PROJ_COMPUTE(buf_) do{                                                 \
  _Pragma("unroll") for (int kk = 0; kk < 2; ++kk){                            \
    bf16x8 af[4], bf_[4];                                                      \
    _Pragma("unroll") for (int mf = 0; mf < 4; ++mf){                          \
      int r = wr*64 + mf*16 + fr;                                              \
      af[mf] = *reinterpret_cast<const bf16x8*>(                               \
          &At[buf_][r*64 + ((kk*4 + fc) ^ (r & 7))*8]);                        \
    }                                                                          \
    _Pragma("unroll") for (int nf = 0; nf < 4; ++nf){                          \
      int r = wc*64 + nf*16 + fr;                                              \
      bf_[nf] = *reinterpret_cast<const bf16x8*>(                              \
          &Bt[buf_][r*64 + ((kk*4 + fc) ^ (r & 7))*8]);                        \
    }                                                                          \
    _Pragma("unroll") for (int mf = 0; mf < 4; ++mf)                           \
    _Pragma("unroll") for (int nf = 0; nf < 4; ++nf)                           \
      acc[mf][nf] = __builtin_amdgcn_mfma_f32_16x16x32_bf16(                   \
          af[mf], bf_[nf], acc[mf][nf], 0, 0, 0);                              \
  }                                                                            \
}while(0)

__global__ __launch_bounds__(256) void proj_hm_k(
    const unsigned short* __restrict__ xb,
    const unsigned short* __restrict__ Wqkb,
    const int* __restrict__ tmap, const int* __restrict__ vcount,
    unsigned short* __restrict__ Qhm, unsigned short* __restrict__ Kc,
    float* __restrict__ qn, float* __restrict__ knc){
  const int z = blockIdx.z;
  const int m0 = blockIdx.x * 128, n0 = blockIdx.y * 128;
  const int bb = m0 >> 11, tc0 = m0 & 2047;
  const int vc = vcount[bb];
  if (z == 1 && tc0 >= vc) return;
  const unsigned short* Bw = Wqkb + (size_t)z*E_*E_;
  unsigned short* Out = z ? Kc : Qhm;
  float* Nrm = z ? knc : qn;

  __shared__ unsigned short At[3][128*64];   // 24KB
  __shared__ unsigned short Bt[3][128*64];   // 24KB -> 48KB total, 3 blocks/CU
  const int tid = threadIdx.x, wave = tid >> 6, lane = tid & 63;
  const int wr = wave >> 1, wc = wave & 1;
  const int fr = lane & 15, fc = lane >> 4;
  const int srow = lane >> 3, sc = lane & 7;

  int arow[4];
  #pragma unroll
  for (int i = 0; i < 4; ++i){
    int r = wave*32 + i*8 + srow;
    int tc = tc0 + r;
    arow[i] = z ? ((tc < vc) ? tmap[bb*S_ + tc] : 0) : tc;
  }

  f32x4 acc[4][4] = {};

  // prologue: 2 tiles in flight
  PROJ_STAGE(0, 0);
  PROJ_STAGE(1, 64);
  VMW(8); BAR();                       // tile 0 resident everywhere
  // steady: 16 K-steps, fully unrolled -> ring slots compile-time
  #pragma unroll
  for (int t = 0; t < 16; ++t){
    PROJ_COMPUTE(t % 3);
    BAR();                             // all waves done reading slot t%3
    if (t + 2 < 16){
      PROJ_STAGE((t + 2) % 3, (t + 2)*64);
      VMW(8); BAR();                   // tile t+1 resident (its 8 ops retired)
    } else if (t + 1 < 16){
      VMW(0); BAR();                   // last tile: drain
    }
  }

  const int h = (n0 >> 6) + wc;
  const size_t rowbase = (size_t)((bb << 4) | h)*S_;
  #pragma unroll
  for (int mf = 0; mf < 4; ++mf)
    #pragma unroll
    for (int r = 0; r < 4; ++r){
      int rowb = tc0 + wr*64 + mf*16 + fc*4 + r;
      #pragma unroll
      for (int nf = 0; nf < 4; ++nf)
        Out[(rowbase + rowb)*64 + nf*16 + fr] = f32_to_bf16(acc[mf][nf][r]);
      float s = 0.f;
      #pragma unroll
      for (int nf = 0; nf < 4; ++nf) s += acc[mf][nf][r]*acc[mf][nf][r];
      s += __shfl_xor(s, 1); s += __shfl_xor(s, 2);
      s += __shfl_xor(s, 4); s += __shfl_xor(s, 8);
      if (fr == 0) Nrm[rowbase + rowb] = s;
    }
}

// ------- LDS-ring candidate search: ring-4, 2 chunks per barrier -------
#define STAGE_K(slot_, c_) do{                                                 \
  _Pragma("unroll") for (int j_ = 0; j_ < 2; ++j_){                            \
    int rr_ = wave*16 + j_*8 + srow;                                           \
    gload_lds16(Kh + (size_t)((c_)*64 + rr_)*64 + (sc ^ (rr_ & 7))*8,          \
                &Kt[slot_][(wave*16 + j_*8)*64]);                              \
  }                                                                            \
}while(0)

// phase A: 8 MFMA + 16 flat compares -> one hitmask bit.
#define TESTCHUNK(slot_, c_) do{                                               \
  int t0_ = (c_)*64;                                                           \
  bf16x8 bfr_[4][2]; float knh_[4];                                            \
  _Pragma("unroll") for (int nf_ = 0; nf_ < 4; ++nf_){                         \
    int tl_ = nf_*16 + fr;                                                     \
    _Pragma("unroll") for (int kk_ = 0; kk_ < 2; ++kk_)                        \
      bfr_[nf_][kk_] = *reinterpret_cast<const bf16x8*>(                       \
          &Kt[slot_][tl_*64 + (((kk_*4 + fc) ^ (tl_ & 7))*8)]);                \
    knh_[nf_] = 0.5f*knl[t0_ + tl_];                                           \
  }                                                                            \
  f32x4 acc[4];                                                                \
  _Pragma("unroll") for (int nf_ = 0; nf_ < 4; ++nf_){                         \
    acc[nf_] = __builtin_amdgcn_mfma_f32_16x16x32_bf16(                        \
        afh[0], bfr_[nf_][0], z4, 0, 0, 0);                                    \
    acc[nf_] = __builtin_amdgcn_mfma_f32_16x16x32_bf16(                        \
        afh[1], bfr_[nf_][1], acc[nf_], 0, 0, 0);                              \
  }                                                                            \
  int hit_ = 0;                                                                \
  _Pragma("unroll") for (int nf_ = 0; nf_ < 4; ++nf_)                          \
  _Pragma("unroll") for (int r_ = 0; r_ < 4; ++r_)                             \
    hit_ |= (acc[nf_][r_] > qa[r_] + knh_[nf_]) ? 1 : 0;                       \
  if (__any(hit_)) hitmask |= (1u << (c_));                                    \
}while(0)

// phase B (cold): reload K chunk from global, redo MFMA, emit + list-build.
#define EMITCHUNK(c_) do{                                                      \
  int t0_ = (c_)*64;                                                           \
  bf16x8 bfr_[4][2]; float knh_[4];                                            \
  _Pragma("unroll") for (int nf_ = 0; nf_ < 4; ++nf_){                         \
    int tl_ = nf_*16 + fr;                                                     \
    _Pragma("unroll") for (int kk_ = 0; kk_ < 2; ++kk_)                        \
      bfr_[nf_][kk_] = *reinterpret_cast<const bf16x8*>(                       \
          Kh + (size_t)(t0_ + tl_)*64 + (kk_*4 + fc)*8);                       \
    knh_[nf_] = 0.5f*knl[t0_ + tl_];                                           \
  }                                                                            \
  f32x4 acc[4];                                                                \
  _Pragma("unroll") for (int nf_ = 0; nf_ < 4; ++nf_){                         \
    acc[nf_] = __builtin_amdgcn_mfma_f32_16x16x32_bf16(                        \
        afh[0], bfr_[nf_][0], z4, 0, 0, 0);                                    \
    acc[nf_] = __builtin_amdgcn_mfma_f32_16x16x32_bf16(                        \
        afh[1], bfr_[nf_][1], acc[nf_], 0, 0, 0);                              \
  }                                                                            \
  _Pragma("unroll") for (int nf_ = 0; nf_ < 4; ++nf_)                          \
  _Pragma("unroll") for (int r_ = 0; r_ < 4; ++r_){                            \
    if (acc[nf_][r_] > qa[r_] + knh_[nf_]){                                    \
      int t_ = t0_ + nf_*16 + fr;                                              \
      int s_ = s0 + wave*16 + fc*4 + r_;                                       \
      unsigned idx_ = atomicAdd(cnt, 1u);                                      \
      if (idx_ < MAXCAND)                                                      \
        cand[idx_] = ((unsigned)b << 26) | ((unsigned)h << 22)                 \
                   | ((unsigned)s_ << 11) | (unsigned)t_;                      \
      int qi_ = (bh << 11) | s_;                                               \
      if (atomicCAS((unsigned*)&qslotm[qi_], 0u, 1u) == 0u){                   \
        int sl_ = atomicAdd(&lcnt[h], 1);                                      \
        if (sl_ < SLOTS){                                                      \
          qlist[h*SLOTS + sl_] = (b << 11) | s_;                               \
          float4 zz_ = {0.f,0.f,0.f,0.f};                                      \
          float4* dz_ = reinterpret_cast<float4*>(                             \
              qex + (size_t)(h*SLOTS + sl_)*64);                               \
          for (int jz_ = 0; jz_ < 16; ++jz_) dz_[jz_] = zz_;                   \
          qslotm[qi_] = sl_ + 2;                                               \
        }                                                                      \
      }                                                                        \
      int ki_ = (bh << 11) | t_;                                               \
      if (atomicCAS((unsigned*)&kslotm[ki_], 0u, 1u) == 0u){                   \
        int sl_ = atomicAdd(&lcnt[16 + h], 1);                                 \
        if (sl_ < SLOTS){                                                      \
          klist[h*SLOTS + sl_] = (b << 11) | t_;                               \
          float4 zz_ = {0.f,0.f,0.f,0.f};                                      \
          float4* d0_ = reinterpret_cast<float4*>(                             \
              kex + (size_t)(h*SLOTS + sl_)*64);                               \
          float4* d1_ = reinterpret_cast<float4*>(                             \
              vex + (size_t)(h*SLOTS + sl_)*64);                               \
          for (int jz_ = 0; jz_ < 16; ++jz_){ d0_[jz_] = zz_; d1_[jz_] = zz_; } \
          kslotm[ki_] = sl_ + 2;                                               \
        }                                                                      \
      }                                                                        \
    }                                                                          \
  }                                                                            \
}while(0)

__global__ __launch_bounds__(256) void search_k(
    const unsigned short* __restrict__ Qhm, const unsigned short* __restrict__ Kc,
    const float* __restrict__ qn, const float* __restrict__ knc,
    const int* __restrict__ vcount,
    unsigned* __restrict__ cnt, unsigned* __restrict__ cand,
    int* __restrict__ lcnt, int* __restrict__ qlist, int* __restrict__ klist,
    int* __restrict__ qslotm, int* __restrict__ kslotm,
    float* __restrict__ qex, float* __restrict__ kex, float* __restrict__ vex){
  __shared__ unsigned short Kt[4][64*64];    // 32KB ring (slot0 doubles as Q stage)
  __shared__ float knl[S_];                  // 8KB  -> 40KB total, 4 blocks/CU
  const int wave = threadIdx.x >> 6, lane = threadIdx.x & 63;
  const int bh = blockIdx.x & 63;
  const int s0 = (blockIdx.x >> 6) * 64;     // 32 strip-blocks
  const int b = bh >> 4, h = bh & 15;
  const int vc = vcount[b];
  const int nt = (vc + 63) >> 6;             // <= 32
  if (nt == 0) return;
  const int fr = lane & 15, fc = lane >> 4;
  const int srow = lane >> 3, sc = lane & 7;
  const unsigned short* Qh = Qhm + (size_t)bh*S_*64;
  const unsigned short* Kh = Kc + (size_t)bh*S_*64;
  const float* qnb = qn + (size_t)bh*S_;
  const float* knb = knc + (size_t)bh*S_;
  const f32x4 z4 = {0.f, 0.f, 0.f, 0.f};

  // qa thresholds: force-complete BEFORE staging (clean vmcnt bookkeeping)
  float qa[4];
  #pragma unroll
  for (int r = 0; r < 4; ++r)
    qa[r] = 0.5f*(qnb[s0 + wave*16 + fc*4 + r] - T_SEARCH);
  float qamin = fminf(fminf(qa[0], qa[1]), fminf(qa[2], qa[3]));
  asm volatile("" :: "v"(qamin));
  asm volatile("s_waitcnt vmcnt(0)" ::: "memory");
  __builtin_amdgcn_sched_barrier(0);

  // ---- prologue: Q strip -> Kt[0] (2 ops) + knl (2 ops); read afh; poison knl
  #pragma unroll
  for (int i = 0; i < 2; ++i){
    int r = wave*16 + i*8 + srow;
    gload_lds16(Qh + (size_t)(s0 + r)*64 + (sc ^ (r & 7))*8, &Kt[0][(wave*16 + i*8)*64]);
  }
  gload_lds16(knb + wave*512 + lane*4,       &knl[wave*512]);
  gload_lds16(knb + wave*512 + 256 + lane*4, &knl[wave*512 + 256]);
  VMW(0);                                   // own Q + knl retired
  bf16x8 afh[2];                            // wave reads only its own staged rows
  { int r_ = wave*16 + fr;
    #pragma unroll
    for (int kk = 0; kk < 2; ++kk)
      afh[kk] = *reinterpret_cast<const bf16x8*>(&Kt[0][r_*64 + (((kk*4 + fc) ^ (r_ & 7))*8)]);
  }
  { int lo = vc > wave*512 ? vc : wave*512; // poison own knl section beyond vc
    int hi = nt*64 < (wave+1)*512 ? nt*64 : (wave+1)*512;
    for (int t = lo + lane; t < hi; t += 64) knl[t] = 1e30f;
  }
  asm volatile("s_waitcnt lgkmcnt(0)" ::: "memory");
  __builtin_amdgcn_sched_barrier(0);
  // stage K chunks 0,1 (slot0 overwrite: same-wave region as its afh read)
  STAGE_K(0, 0);
  if (nt > 1) STAGE_K(1, 1);

  unsigned hitmask = 0u;
  int c = 0;
  // ---- main loop: 2 chunks per barrier, unrolled 2x -> static ring slots
  while (c + 5 < nt){
    VMW(0); BAR(); STAGE_K(2, c + 2); STAGE_K(3, c + 3); TESTCHUNK(0, c); TESTCHUNK(1, c + 1);
    VMW(0); BAR(); STAGE_K(0, c + 4); STAGE_K(1, c + 5); TESTCHUNK(2, c + 2); TESTCHUNK(3, c + 3);
    c += 4;
  }
  // ---- tail (<=5 chunks), runtime slots, single-chunk steps
  for (; c + 2 < nt; ++c){
    VMW(2); BAR();
    STAGE_K((c + 2) & 3, c + 2);
    TESTCHUNK(c & 3, c);
  }
  if (c + 1 < nt){ VMW(2); BAR(); TESTCHUNK(c & 3, c); ++c; }
  VMW(0); BAR(); TESTCHUNK(c & 3, c);

  // ---- phase B: cold emit over hit chunks (wave-uniform mask, K from global)
  while (hitmask){
    int cc = __builtin_ctz(hitmask);
    hitmask &= hitmask - 1u;
    EMITCHUNK(cc);
  }
}

// ---------------- exact fp32 rows, head-grouped, E-part-split ----------------
__global__ __launch_bounds__(256) void exact_rows_k(
    const float* __restrict__ x, const int* __restrict__ tmap,
    const float* __restrict__ Wq, const float* __restrict__ Wk,
    const float* __restrict__ Wv,
    const int* __restrict__ lcnt,
    const int* __restrict__ qlist, const int* __restrict__ klist,
    float* __restrict__ qex, float* __restrict__ kex, float* __restrict__ vex){
  int p = blockIdx.x, h = blockIdx.y, z = blockIdx.z;
  int R = lcnt[(z == 0 ? 0 : 16) + h]; if (R > SLOTS) R = SLOTS;
  if (R == 0) return;
  const float* W = (z == 0) ? Wq : (z == 1 ? Wk : Wv);
  const int* list = (z == 0) ? qlist : klist;
  float* dst = (z == 0) ? qex : (z == 1 ? kex : vex);
  int d = threadIdx.x >> 2, j = threadIdx.x & 3;
  const float4* w4 = reinterpret_cast<const float4*>(W + (size_t)(h*64 + d)*E_ + p*64 + j*16);
  float4 wa = w4[0], wb = w4[1], wcv = w4[2], wd = w4[3];
  for (int r = 0; r < R; ++r){
    int e = list[h*SLOTS + r];
    int b = e >> 11, rr = e & 2047;
    int row = (z == 0) ? rr : tmap[b*S_ + rr];
    const float4* x4 = reinterpret_cast<const float4*>(x + (size_t)(b*S_ + row)*E_ + p*64 + j*16);
    float acc = dot4(x4[0], wa) + dot4(x4[1], wb) + dot4(x4[2], wcv) + dot4(x4[3], wd);
    acc += __shfl_xor(acc, 1);
    acc += __shfl_xor(acc, 2);
    if (j == 0) atomicAdd(&dst[(size_t)(h*SLOTS + r)*64 + d], acc);
  }
}

// ------- fused exact d2 + exp + scatter: out[b,s,:] += w * (v @ Wo^T) -------
__global__ __launch_bounds__(256) void d2scatter_k(
    const unsigned* __restrict__ cnt, const unsigned* __restrict__ cand,
    const int* __restrict__ qslotm, const int* __restrict__ kslotm,
    const float* __restrict__ qex, const float* __restrict__ kex,
    const float* __restrict__ vex, const float* __restrict__ Wo,
    float* __restrict__ out){
  unsigned n = *cnt; if (n > MAXCAND) n = MAXCAND;
  int lane = threadIdx.x & 63;
  for (unsigned i = blockIdx.x; i < n; i += gridDim.x){
    unsigned u = cand[i];
    int b = (int)(u >> 26), h = (int)((u >> 22) & 15);
    int s = (int)((u >> 11) & 2047), tc = (int)(u & 2047);
    int qi = ((b*16 + h) << 11) | s, ki = ((b*16 + h) << 11) | tc;
    int qs = qslotm[qi] - 2, ks = kslotm[ki] - 2;   // <0: overflow/invalid
    float sq;
    if (qs >= 0 && ks >= 0){
      float a = qex[(size_t)(h*SLOTS + qs)*64 + lane] - kex[(size_t)(h*SLOTS + ks)*64 + lane];
      sq = a*a;
    } else sq = 1e30f;
    #pragma unroll
    for (int o = 32; o; o >>= 1) sq += __shfl_xor(sq, o);
    if (sq >= T_CUT) continue;
    float w = expf(-sq);
    const float4* vv4 = reinterpret_cast<const float4*>(vex + (size_t)(h*SLOTS + ks)*64);
    #pragma unroll
    for (int c4 = 0; c4 < 4; ++c4){
      int e = c4*256 + threadIdx.x;
      const float4* wo4 = reinterpret_cast<const float4*>(Wo + (size_t)e*E_ + h*64);
      float a = 0.f;
      #pragma unroll
      for (int d2 = 0; d2 < 16; ++d2){
        float4 vv = vv4[d2], ww = wo4[d2];
        a += vv.x*ww.x + vv.y*ww.y + vv.z*ww.z + vv.w*ww.w;
      }
      atomicAdd(&out[(size_t)(b*S_ + s)*E_ + e], w*a);
    }
  }
}

extern "C" void kernel_launch(void* const* d_in, const int* in_sizes, int n_in,
                              void* d_out, int out_size, void* d_ws, size_t ws_size,
                              hipStream_t stream){
  const float* x  = (const float*)d_in[0];
  const int* mask = (const int*)d_in[1];
  const float* Wq = (const float*)d_in[2];
  const float* Wk = (const float*)d_in[3];
  const float* Wv = (const float*)d_in[4];
  const float* Wo = (const float*)d_in[5];
  float* out = (float*)d_out;

  char* w = (char*)d_ws;
  unsigned short* Qhm = (unsigned short*)w; w += (size_t)BS_*E_*2;   // head-major [b,h][s][64]
  unsigned short* Kc  = (unsigned short*)w; w += (size_t)BS_*E_*2;   // head-major compacted K
  unsigned short* xb  = (unsigned short*)w; w += (size_t)BS_*E_*2;   // bf16 x, row-major
  unsigned short* Wqkb = (unsigned short*)w; w += (size_t)E_*E_*2*2; // Wq | Wk bf16
  float* qn  = (float*)w; w += (size_t)BHS_*4;
  float* knc = (float*)w; w += (size_t)BHS_*4;
  int* tmap   = (int*)w; w += (size_t)BS_*4;
  int* vcount = (int*)w; w += 256;
  unsigned* cand = (unsigned*)w; w += (size_t)MAXCAND*4;
  int* qlist  = (int*)w; w += (size_t)H_*SLOTS*4;
  int* klist  = (int*)w; w += (size_t)H_*SLOTS*4;
  float* qex = (float*)w; w += (size_t)H_*SLOTS*64*4;   // zeroed lazily in search emit
  float* kex = (float*)w; w += (size_t)H_*SLOTS*64*4;
  float* vex = (float*)w; w += (size_t)H_*SLOTS*64*4;
  // ---- contiguous zeroed region (single memset): counters + slot maps
  char* zbase = w;
  unsigned* cnt  = (unsigned*)w; w += 256;
  int* lcnt = (int*)w; w += 256;
  int* qslotm = (int*)w; w += (size_t)BHS_*4;
  int* kslotm = (int*)w; w += (size_t)BHS_*4;
  size_t zbytes = (size_t)(w - zbase);

  hipMemsetAsync(zbase, 0, zbytes, stream);

  // casts + mask compaction + d_out zeroing (one launch)
  cast_compact_k<<<5124 + 2048, 256, 0, stream>>>(x, Wq, Wk, mask, xb, Wqkb, tmap, vcount, out);

  // fused Q|K projection, ring-3 pipelined, head-major out + norms (one launch)
  proj_hm_k<<<dim3(64, 8, 2), 256, 0, stream>>>(xb, Wqkb, tmap, vcount, Qhm, Kc, qn, knc);

  // LDS-ring pair search (ring-4, 2 chunks/barrier); emit builds dedup row-lists
  search_k<<<32*64, 256, 0, stream>>>(Qhm, Kc, qn, knc, vcount, cnt, cand,
                                      lcnt, qlist, klist, qslotm, kslotm, qex, kex, vex);

  // sparse exact pipeline
  exact_rows_k<<<dim3(16, 16, 3), 256, 0, stream>>>(x, tmap, Wq, Wk, Wv, lcnt, qlist, klist, qex, kex, vex);
  d2scatter_k<<<512, 256, 0, stream>>>(cnt, cand, qslotm, kslotm, qex, kex, vex, Wo, out);
}

// Round 19
// 157.205 us; speedup vs baseline: 1.1688x; 1.1688x over previous
//
#include <hip/hip_runtime.h>
#include <hip/hip_bf16.h>
#include <cstdint>
#include <cstddef>

#define B_ 4
#define S_ 2048
#define E_ 1024
#define H_ 16
#define BS_ (B_*S_)
#define BHS_ (B_*H_*S_)
#define MAXCAND (1u<<18)
#define SLOTS 512

static constexpr float T_SEARCH = 50.0f;  // bf16 search threshold (~8-sigma over cut)
static constexpr float T_CUT    = 48.5f;  // exact fp32 cut; e^-48.5 contribution ~300x under tol

typedef __attribute__((ext_vector_type(8))) short bf16x8;
typedef __attribute__((ext_vector_type(4))) float f32x4;

static __device__ __forceinline__ unsigned short f32_to_bf16(float f){
  unsigned u = __float_as_uint(f);
  return (unsigned short)((u + 0x7fffu + ((u >> 16) & 1u)) >> 16);  // RNE
}
static __device__ __forceinline__ void gload_lds16(const void* g, void* l){
  __builtin_amdgcn_global_load_lds(
      (const __attribute__((address_space(1))) unsigned int*)g,
      (__attribute__((address_space(3))) unsigned int*)l, 16, 0, 0);
}
static __device__ __forceinline__ float dot4(float4 a, float4 b){
  return a.x*b.x + a.y*b.y + a.z*b.z + a.w*b.w;
}

#define VMW(N_) asm volatile("s_waitcnt vmcnt(" #N_ ")" ::: "memory")
#define BAR()  do{ __builtin_amdgcn_s_barrier(); __builtin_amdgcn_sched_barrier(0); }while(0)

// --- fused: f32->bf16 casts (x, Wq, Wk) + mask compaction + d_out zeroing ---
__global__ void cast_compact_k(const float* __restrict__ x,
                               const float* __restrict__ wq, const float* __restrict__ wk,
                               const int* __restrict__ mask,
                               unsigned short* __restrict__ xb, unsigned short* __restrict__ wqkb,
                               int* __restrict__ tmap, int* __restrict__ vcount,
                               float* __restrict__ outz){
  int blk = blockIdx.x;
  if (blk >= 5124){                     // zero d_out: 2048 blocks x 16KB
    float4* f4 = reinterpret_cast<float4*>(outz + (size_t)(blk - 5124)*4096);
    float4 z = {0.f,0.f,0.f,0.f};
    f4[threadIdx.x]       = z;
    f4[threadIdx.x + 256] = z;
    f4[threadIdx.x + 512] = z;
    f4[threadIdx.x + 768] = z;
    return;
  }
  if (blk >= 5120){                     // mask compaction, b = blk-5120
    int b = blk - 5120, tid = threadIdx.x;
    __shared__ int ps[256];
    int loc[8]; int cnt = 0;
    #pragma unroll
    for (int j = 0; j < 8; ++j){ int m = mask[b*S_ + tid*8 + j]; loc[j] = m; cnt += m; }
    ps[tid] = cnt; __syncthreads();
    for (int off = 1; off < 256; off <<= 1){
      int v = (tid >= off) ? ps[tid-off] : 0;
      __syncthreads(); ps[tid] += v; __syncthreads();
    }
    int base = ps[tid] - cnt;
    #pragma unroll
    for (int j = 0; j < 8; ++j)
      if (loc[j]){ tmap[b*S_ + base] = tid*8 + j; ++base; }
    if (tid == 255) vcount[b] = ps[255];
    return;
  }
  const float* src; unsigned short* dst; int base;
  if (blk < 4096){ src = x;  dst = xb;                  base = blk; }
  else if (blk < 4608){ src = wq; dst = wqkb;           base = blk - 4096; }
  else { src = wk; dst = wqkb + (size_t)E_*E_;          base = blk - 4608; }
  size_t i = (size_t)base*256 + threadIdx.x;            // 8 elems per item
  const float4* s4 = reinterpret_cast<const float4*>(src) + 2*i;
  float4 a = s4[0], b = s4[1];
  float v[8] = {a.x,a.y,a.z,a.w,b.x,b.y,b.z,b.w};
  union { unsigned short us[8]; uint4 u4; } o;
  #pragma unroll
  for (int j = 0; j < 8; ++j) o.us[j] = f32_to_bf16(v[j]);
  reinterpret_cast<uint4*>(dst)[i] = o.u4;
}

// ------- fused Q|K projection, 2-buffer pipelined staging, norms in epilogue -------
#define PROJ_STAGE(buf_, k0_) do{                                              \
  _Pragma("unroll") for (int i_ = 0; i_ < 4; ++i_){                            \
    int r_  = wave*32 + i_*8 + srow;                                           \
    int cs_ = sc ^ (r_ & 7);                                                   \
    gload_lds16(xb + ((size_t)(bb << 11) + arow[i_])*1024 + (k0_) + cs_*8,     \
                &At[buf_][(wave*32 + i_*8)*64]);                               \
    gload_lds16(Bw + (size_t)(n0 + r_)*1024 + (k0_) + cs_*8,                   \
                &Bt[buf_][(wave*32 + i_*8)*64]);                               \
  }                                                                            \
}while(0)

#define PROJ_COMPUTE(buf_) do{                                                 \
  _Pragma("unroll") for (int kk = 0; kk < 2; ++kk){                            \
    bf16x8 af[4], bf_[4];                                                      \
    _Pragma("unroll") for (int mf = 0; mf < 4; ++mf){                          \
      int r = wr*64 + mf*16 + fr;                                              \
      af[mf] = *reinterpret_cast<const bf16x8*>(                               \
          &At[buf_][r*64 + ((kk*4 + fc) ^ (r & 7))*8]);                        \
    }                                                                          \
    _Pragma("unroll") for (int nf = 0; nf < 4; ++nf){                          \
      int r = wc*64 + nf*16 + fr;                                              \
      bf_[nf] = *reinterpret_cast<const bf16x8*>(                              \
          &Bt[buf_][r*64 + ((kk*4 + fc) ^ (r & 7))*8]);                        \
    }                                                                          \
    _Pragma("unroll") for (int mf = 0; mf < 4; ++mf)                           \
    _Pragma("unroll") for (int nf = 0; nf < 4; ++nf)                           \
      acc[mf][nf] = __builtin_amdgcn_mfma_f32_16x16x32_bf16(                   \
          af[mf], bf_[nf], acc[mf][nf], 0, 0, 0);                              \
  }                                                                            \
}while(0)

__global__ __launch_bounds__(256) void proj_hm_k(
    const unsigned short* __restrict__ xb,
    const unsigned short* __restrict__ Wqkb,
    const int* __restrict__ tmap, const int* __restrict__ vcount,
    unsigned short* __restrict__ Qhm, unsigned short* __restrict__ Kc,
    float* __restrict__ qn, float* __restrict__ knc){
  const int z = blockIdx.z;
  const int m0 = blockIdx.x * 128, n0 = blockIdx.y * 128;
  const int bb = m0 >> 11, tc0 = m0 & 2047;
  const int vc = vcount[bb];
  if (z == 1 && tc0 >= vc) return;
  const unsigned short* Bw = Wqkb + (size_t)z*E_*E_;
  unsigned short* Out = z ? Kc : Qhm;
  float* Nrm = z ? knc : qn;

  __shared__ unsigned short At[2][128*64];   // 32KB
  __shared__ unsigned short Bt[2][128*64];   // 32KB -> 64KB total, 2 blocks/CU
  const int tid = threadIdx.x, wave = tid >> 6, lane = tid & 63;
  const int wr = wave >> 1, wc = wave & 1;
  const int fr = lane & 15, fc = lane >> 4;
  const int srow = lane >> 3, sc = lane & 7;

  int arow[4];
  #pragma unroll
  for (int i = 0; i < 4; ++i){
    int r = wave*32 + i*8 + srow;
    int tc = tc0 + r;
    arow[i] = z ? ((tc < vc) ? tmap[bb*S_ + tc] : 0) : tc;
  }

  f32x4 acc[4][4] = {};

  PROJ_STAGE(0, 0);
  PROJ_STAGE(1, 64);
  VMW(8); BAR();
  #pragma unroll 2
  for (int t = 0; t < 16; ++t){
    PROJ_COMPUTE(t & 1);
    BAR();
    if (t + 2 < 16){
      PROJ_STAGE(t & 1, (t + 2)*64);
      VMW(8); BAR();
    } else if (t + 1 < 16){
      VMW(0); BAR();
    }
  }

  const int h = (n0 >> 6) + wc;
  const size_t rowbase = (size_t)((bb << 4) | h)*S_;
  #pragma unroll
  for (int mf = 0; mf < 4; ++mf)
    #pragma unroll
    for (int r = 0; r < 4; ++r){
      int rowb = tc0 + wr*64 + mf*16 + fc*4 + r;
      #pragma unroll
      for (int nf = 0; nf < 4; ++nf)
        Out[(rowbase + rowb)*64 + nf*16 + fr] = f32_to_bf16(acc[mf][nf][r]);
      float s = 0.f;
      #pragma unroll
      for (int nf = 0; nf < 4; ++nf) s += acc[mf][nf][r]*acc[mf][nf][r];
      s += __shfl_xor(s, 1); s += __shfl_xor(s, 2);
      s += __shfl_xor(s, 4); s += __shfl_xor(s, 8);
      if (fr == 0) Nrm[rowbase + rowb] = s;
    }
}

// ------- LDS-ring candidate search: ring-4, 2 chunks per barrier -------
// Q stages through ring slot 0 (read to afh before first K overwrite, same-wave
// region). slot = chunk & 3; main pair-loop unrolled 2x -> static slots.
#define STAGE_K(slot_, c_) do{                                                 \
  _Pragma("unroll") for (int j_ = 0; j_ < 2; ++j_){                            \
    int rr_ = wave*16 + j_*8 + srow;                                           \
    gload_lds16(Kh + (size_t)((c_)*64 + rr_)*64 + (sc ^ (rr_ & 7))*8,          \
                &Kt[slot_][(wave*16 + j_*8)*64]);                              \
  }                                                                            \
}while(0)

// phase A: 8 MFMA + 16 flat compares -> one hitmask bit.
#define TESTCHUNK(slot_, c_) do{                                               \
  int t0_ = (c_)*64;                                                           \
  bf16x8 bfr_[4][2]; float knh_[4];                                            \
  _Pragma("unroll") for (int nf_ = 0; nf_ < 4; ++nf_){                         \
    int tl_ = nf_*16 + fr;                                                     \
    _Pragma("unroll") for (int kk_ = 0; kk_ < 2; ++kk_)                        \
      bfr_[nf_][kk_] = *reinterpret_cast<const bf16x8*>(                       \
          &Kt[slot_][tl_*64 + (((kk_*4 + fc) ^ (tl_ & 7))*8)]);                \
    knh_[nf_] = 0.5f*knl[t0_ + tl_];                                           \
  }                                                                            \
  f32x4 acc[4];                                                                \
  _Pragma("unroll") for (int nf_ = 0; nf_ < 4; ++nf_){                         \
    acc[nf_] = __builtin_amdgcn_mfma_f32_16x16x32_bf16(                        \
        afh[0], bfr_[nf_][0], z4, 0, 0, 0);                                    \
    acc[nf_] = __builtin_amdgcn_mfma_f32_16x16x32_bf16(                        \
        afh[1], bfr_[nf_][1], acc[nf_], 0, 0, 0);                              \
  }                                                                            \
  int hit_ = 0;                                                                \
  _Pragma("unroll") for (int nf_ = 0; nf_ < 4; ++nf_)                          \
  _Pragma("unroll") for (int r_ = 0; r_ < 4; ++r_)                             \
    hit_ |= (acc[nf_][r_] > qa[r_] + knh_[nf_]) ? 1 : 0;                       \
  if (__any(hit_)) hitmask |= (1u << (c_));                                    \
}while(0)

// phase B (cold): reload K chunk from global, redo MFMA, emit + list-build.
#define EMITCHUNK(c_) do{                                                      \
  int t0_ = (c_)*64;                                                           \
  bf16x8 bfr_[4][2]; float knh_[4];                                            \
  _Pragma("unroll") for (int nf_ = 0; nf_ < 4; ++nf_){                         \
    int tl_ = nf_*16 + fr;                                                     \
    _Pragma("unroll") for (int kk_ = 0; kk_ < 2; ++kk_)                        \
      bfr_[nf_][kk_] = *reinterpret_cast<const bf16x8*>(                       \
          Kh + (size_t)(t0_ + tl_)*64 + (kk_*4 + fc)*8);                       \
    knh_[nf_] = 0.5f*knl[t0_ + tl_];                                           \
  }                                                                            \
  f32x4 acc[4];                                                                \
  _Pragma("unroll") for (int nf_ = 0; nf_ < 4; ++nf_){                         \
    acc[nf_] = __builtin_amdgcn_mfma_f32_16x16x32_bf16(                        \
        afh[0], bfr_[nf_][0], z4, 0, 0, 0);                                    \
    acc[nf_] = __builtin_amdgcn_mfma_f32_16x16x32_bf16(                        \
        afh[1], bfr_[nf_][1], acc[nf_], 0, 0, 0);                              \
  }                                                                            \
  _Pragma("unroll") for (int nf_ = 0; nf_ < 4; ++nf_)                          \
  _Pragma("unroll") for (int r_ = 0; r_ < 4; ++r_){                            \
    if (acc[nf_][r_] > qa[r_] + knh_[nf_]){                                    \
      int t_ = t0_ + nf_*16 + fr;                                              \
      int s_ = s0 + wave*16 + fc*4 + r_;                                       \
      unsigned idx_ = atomicAdd(cnt, 1u);                                      \
      if (idx_ < MAXCAND)                                                      \
        cand[idx_] = ((unsigned)b << 26) | ((unsigned)h << 22)                 \
                   | ((unsigned)s_ << 11) | (unsigned)t_;                      \
      int qi_ = (bh << 11) | s_;                                               \
      if (atomicCAS((unsigned*)&qslotm[qi_], 0u, 1u) == 0u){                   \
        int sl_ = atomicAdd(&lcnt[h], 1);                                      \
        if (sl_ < SLOTS){                                                      \
          qlist[h*SLOTS + sl_] = (b << 11) | s_;                               \
          float4 zz_ = {0.f,0.f,0.f,0.f};                                      \
          float4* dz_ = reinterpret_cast<float4*>(                             \
              qex + (size_t)(h*SLOTS + sl_)*64);                               \
          for (int jz_ = 0; jz_ < 16; ++jz_) dz_[jz_] = zz_;                   \
          qslotm[qi_] = sl_ + 2;                                               \
        }                                                                      \
      }                                                                        \
      int ki_ = (bh << 11) | t_;                                               \
      if (atomicCAS((unsigned*)&kslotm[ki_], 0u, 1u) == 0u){                   \
        int sl_ = atomicAdd(&lcnt[16 + h], 1);                                 \
        if (sl_ < SLOTS){                                                      \
          klist[h*SLOTS + sl_] = (b << 11) | t_;                               \
          float4 zz_ = {0.f,0.f,0.f,0.f};                                      \
          float4* d0_ = reinterpret_cast<float4*>(                             \
              kex + (size_t)(h*SLOTS + sl_)*64);                               \
          float4* d1_ = reinterpret_cast<float4*>(                             \
              vex + (size_t)(h*SLOTS + sl_)*64);                               \
          for (int jz_ = 0; jz_ < 16; ++jz_){ d0_[jz_] = zz_; d1_[jz_] = zz_; } \
          kslotm[ki_] = sl_ + 2;                                               \
        }                                                                      \
      }                                                                        \
    }                                                                          \
  }                                                                            \
}while(0)

__global__ __launch_bounds__(256) void search_k(
    const unsigned short* __restrict__ Qhm, const unsigned short* __restrict__ Kc,
    const float* __restrict__ qn, const float* __restrict__ knc,
    const int* __restrict__ vcount,
    unsigned* __restrict__ cnt, unsigned* __restrict__ cand,
    int* __restrict__ lcnt, int* __restrict__ qlist, int* __restrict__ klist,
    int* __restrict__ qslotm, int* __restrict__ kslotm,
    float* __restrict__ qex, float* __restrict__ kex, float* __restrict__ vex){
  __shared__ unsigned short Kt[4][64*64];    // 32KB ring (slot0 doubles as Q stage)
  __shared__ float knl[S_];                  // 8KB  -> 40KB total, 4 blocks/CU
  const int wave = threadIdx.x >> 6, lane = threadIdx.x & 63;
  const int bh = blockIdx.x & 63;
  const int s0 = (blockIdx.x >> 6) * 64;     // 32 strip-blocks
  const int b = bh >> 4, h = bh & 15;
  const int vc = vcount[b];
  const int nt = (vc + 63) >> 6;             // <= 32
  if (nt == 0) return;
  const int fr = lane & 15, fc = lane >> 4;
  const int srow = lane >> 3, sc = lane & 7;
  const unsigned short* Qh = Qhm + (size_t)bh*S_*64;
  const unsigned short* Kh = Kc + (size_t)bh*S_*64;
  const float* qnb = qn + (size_t)bh*S_;
  const float* knb = knc + (size_t)bh*S_;
  const f32x4 z4 = {0.f, 0.f, 0.f, 0.f};

  // qa thresholds: force-complete BEFORE staging (clean vmcnt bookkeeping)
  float qa[4];
  #pragma unroll
  for (int r = 0; r < 4; ++r)
    qa[r] = 0.5f*(qnb[s0 + wave*16 + fc*4 + r] - T_SEARCH);
  float qamin = fminf(fminf(qa[0], qa[1]), fminf(qa[2], qa[3]));
  asm volatile("" :: "v"(qamin));
  asm volatile("s_waitcnt vmcnt(0)" ::: "memory");
  __builtin_amdgcn_sched_barrier(0);

  // ---- prologue: Q strip -> Kt[0] (2 ops) + knl (2 ops); read afh; poison knl
  #pragma unroll
  for (int i = 0; i < 2; ++i){
    int r = wave*16 + i*8 + srow;
    gload_lds16(Qh + (size_t)(s0 + r)*64 + (sc ^ (r & 7))*8, &Kt[0][(wave*16 + i*8)*64]);
  }
  gload_lds16(knb + wave*512 + lane*4,       &knl[wave*512]);
  gload_lds16(knb + wave*512 + 256 + lane*4, &knl[wave*512 + 256]);
  VMW(0);                                   // own Q + knl retired
  bf16x8 afh[2];                            // wave reads only its own staged rows
  { int r_ = wave*16 + fr;
    #pragma unroll
    for (int kk = 0; kk < 2; ++kk)
      afh[kk] = *reinterpret_cast<const bf16x8*>(&Kt[0][r_*64 + (((kk*4 + fc) ^ (r_ & 7))*8)]);
  }
  { int lo = vc > wave*512 ? vc : wave*512; // poison own knl section beyond vc
    int hi = nt*64 < (wave+1)*512 ? nt*64 : (wave+1)*512;
    for (int t = lo + lane; t < hi; t += 64) knl[t] = 1e30f;
  }
  asm volatile("s_waitcnt lgkmcnt(0)" ::: "memory");
  __builtin_amdgcn_sched_barrier(0);
  // stage K chunks 0,1 (slot0 overwrite: same-wave region as its afh read)
  STAGE_K(0, 0);
  if (nt > 1) STAGE_K(1, 1);

  unsigned hitmask = 0u;
  int c = 0;
  // ---- main loop: 2 chunks per barrier, unrolled 2x -> static ring slots
  while (c + 5 < nt){
    VMW(0); BAR(); STAGE_K(2, c + 2); STAGE_K(3, c + 3); TESTCHUNK(0, c); TESTCHUNK(1, c + 1);
    VMW(0); BAR(); STAGE_K(0, c + 4); STAGE_K(1, c + 5); TESTCHUNK(2, c + 2); TESTCHUNK(3, c + 3);
    c += 4;
  }
  // ---- tail (<=5 chunks), runtime slots, single-chunk steps
  for (; c + 2 < nt; ++c){
    VMW(2); BAR();
    STAGE_K((c + 2) & 3, c + 2);
    TESTCHUNK(c & 3, c);
  }
  if (c + 1 < nt){ VMW(2); BAR(); TESTCHUNK(c & 3, c); ++c; }
  VMW(0); BAR(); TESTCHUNK(c & 3, c);

  // ---- phase B: cold emit over hit chunks (wave-uniform mask, K from global)
  while (hitmask){
    int cc = __builtin_ctz(hitmask);
    hitmask &= hitmask - 1u;
    EMITCHUNK(cc);
  }
}

// ---------------- exact fp32 rows, head-grouped, E-part-split ----------------
__global__ __launch_bounds__(256) void exact_rows_k(
    const float* __restrict__ x, const int* __restrict__ tmap,
    const float* __restrict__ Wq, const float* __restrict__ Wk,
    const float* __restrict__ Wv,
    const int* __restrict__ lcnt,
    const int* __restrict__ qlist, const int* __restrict__ klist,
    float* __restrict__ qex, float* __restrict__ kex, float* __restrict__ vex){
  int p = blockIdx.x, h = blockIdx.y, z = blockIdx.z;
  int R = lcnt[(z == 0 ? 0 : 16) + h]; if (R > SLOTS) R = SLOTS;
  if (R == 0) return;
  const float* W = (z == 0) ? Wq : (z == 1 ? Wk : Wv);
  const int* list = (z == 0) ? qlist : klist;
  float* dst = (z == 0) ? qex : (z == 1 ? kex : vex);
  int d = threadIdx.x >> 2, j = threadIdx.x & 3;
  const float4* w4 = reinterpret_cast<const float4*>(W + (size_t)(h*64 + d)*E_ + p*64 + j*16);
  float4 wa = w4[0], wb = w4[1], wcv = w4[2], wd = w4[3];
  for (int r = 0; r < R; ++r){
    int e = list[h*SLOTS + r];
    int b = e >> 11, rr = e & 2047;
    int row = (z == 0) ? rr : tmap[b*S_ + rr];
    const float4* x4 = reinterpret_cast<const float4*>(x + (size_t)(b*S_ + row)*E_ + p*64 + j*16);
    float acc = dot4(x4[0], wa) + dot4(x4[1], wb) + dot4(x4[2], wcv) + dot4(x4[3], wd);
    acc += __shfl_xor(acc, 1);
    acc += __shfl_xor(acc, 2);
    if (j == 0) atomicAdd(&dst[(size_t)(h*SLOTS + r)*64 + d], acc);
  }
}

// ------- fused exact d2 + exp + scatter: out[b,s,:] += w * (v @ Wo^T) -------
__global__ __launch_bounds__(256) void d2scatter_k(
    const unsigned* __restrict__ cnt, const unsigned* __restrict__ cand,
    const int* __restrict__ qslotm, const int* __restrict__ kslotm,
    const float* __restrict__ qex, const float* __restrict__ kex,
    const float* __restrict__ vex, const float* __restrict__ Wo,
    float* __restrict__ out){
  unsigned n = *cnt; if (n > MAXCAND) n = MAXCAND;
  int lane = threadIdx.x & 63;
  for (unsigned i = blockIdx.x; i < n; i += gridDim.x){
    unsigned u = cand[i];
    int b = (int)(u >> 26), h = (int)((u >> 22) & 15);
    int s = (int)((u >> 11) & 2047), tc = (int)(u & 2047);
    int qi = ((b*16 + h) << 11) | s, ki = ((b*16 + h) << 11) | tc;
    int qs = qslotm[qi] - 2, ks = kslotm[ki] - 2;   // <0: overflow/invalid
    float sq;
    if (qs >= 0 && ks >= 0){
      float a = qex[(size_t)(h*SLOTS + qs)*64 + lane] - kex[(size_t)(h*SLOTS + ks)*64 + lane];
      sq = a*a;
    } else sq = 1e30f;
    #pragma unroll
    for (int o = 32; o; o >>= 1) sq += __shfl_xor(sq, o);
    if (sq >= T_CUT) continue;
    float w = expf(-sq);
    const float4* vv4 = reinterpret_cast<const float4*>(vex + (size_t)(h*SLOTS + ks)*64);
    #pragma unroll
    for (int c4 = 0; c4 < 4; ++c4){
      int e = c4*256 + threadIdx.x;
      const float4* wo4 = reinterpret_cast<const float4*>(Wo + (size_t)e*E_ + h*64);
      float a = 0.f;
      #pragma unroll
      for (int d2 = 0; d2 < 16; ++d2){
        float4 vv = vv4[d2], ww = wo4[d2];
        a += vv.x*ww.x + vv.y*ww.y + vv.z*ww.z + vv.w*ww.w;
      }
      atomicAdd(&out[(size_t)(b*S_ + s)*E_ + e], w*a);
    }
  }
}

extern "C" void kernel_launch(void* const* d_in, const int* in_sizes, int n_in,
                              void* d_out, int out_size, void* d_ws, size_t ws_size,
                              hipStream_t stream){
  const float* x  = (const float*)d_in[0];
  const int* mask = (const int*)d_in[1];
  const float* Wq = (const float*)d_in[2];
  const float* Wk = (const float*)d_in[3];
  const float* Wv = (const float*)d_in[4];
  const float* Wo = (const float*)d_in[5];
  float* out = (float*)d_out;

  char* w = (char*)d_ws;
  unsigned short* Qhm = (unsigned short*)w; w += (size_t)BS_*E_*2;   // head-major [b,h][s][64]
  unsigned short* Kc  = (unsigned short*)w; w += (size_t)BS_*E_*2;   // head-major compacted K
  unsigned short* xb  = (unsigned short*)w; w += (size_t)BS_*E_*2;   // bf16 x, row-major
  unsigned short* Wqkb = (unsigned short*)w; w += (size_t)E_*E_*2*2; // Wq | Wk bf16
  float* qn  = (float*)w; w += (size_t)BHS_*4;
  float* knc = (float*)w; w += (size_t)BHS_*4;
  int* tmap   = (int*)w; w += (size_t)BS_*4;
  int* vcount = (int*)w; w += 256;
  unsigned* cand = (unsigned*)w; w += (size_t)MAXCAND*4;
  int* qlist  = (int*)w; w += (size_t)H_*SLOTS*4;
  int* klist  = (int*)w; w += (size_t)H_*SLOTS*4;
  float* qex = (float*)w; w += (size_t)H_*SLOTS*64*4;   // zeroed lazily in search emit
  float* kex = (float*)w; w += (size_t)H_*SLOTS*64*4;
  float* vex = (float*)w; w += (size_t)H_*SLOTS*64*4;
  // ---- contiguous zeroed region (single memset): counters + slot maps
  char* zbase = w;
  unsigned* cnt  = (unsigned*)w; w += 256;
  int* lcnt = (int*)w; w += 256;
  int* qslotm = (int*)w; w += (size_t)BHS_*4;
  int* kslotm = (int*)w; w += (size_t)BHS_*4;
  size_t zbytes = (size_t)(w - zbase);

  hipMemsetAsync(zbase, 0, zbytes, stream);

  // casts + mask compaction + d_out zeroing (one launch)
  cast_compact_k<<<5124 + 2048, 256, 0, stream>>>(x, Wq, Wk, mask, xb, Wqkb, tmap, vcount, out);

  // fused Q|K projection, 2-buffer pipelined, head-major out + norms (one launch)
  proj_hm_k<<<dim3(64, 8, 2), 256, 0, stream>>>(xb, Wqkb, tmap, vcount, Qhm, Kc, qn, knc);

  // LDS-ring pair search (ring-4, 2 chunks/barrier); emit builds dedup row-lists
  search_k<<<32*64, 256, 0, stream>>>(Qhm, Kc, qn, knc, vcount, cnt, cand,
                                      lcnt, qlist, klist, qslotm, kslotm, qex, kex, vex);

  // sparse exact pipeline
  exact_rows_k<<<dim3(16, 16, 3), 256, 0, stream>>>(x, tmap, Wq, Wk, Wv, lcnt, qlist, klist, qex, kex, vex);
  d2scatter_k<<<512, 256, 0, stream>>>(cnt, cand, qslotm, kslotm, qex, kex, vex, Wo, out);
}